// Round 9
// baseline (319.682 us; speedup 1.0000x reference)
//
#include <hip/hip_runtime.h>
#include <math.h>

#define B_DIM 32
#define T_DIM 2048
#define D_DIM 512
#define V_DIM 5
#define L_DIM 256
#define LN2D 0.6931471805599453
#define TP8 (T_DIM + 8)

typedef const float __attribute__((address_space(1)))* gas_fp;
typedef float __attribute__((address_space(3)))* las_fp;

// ---- DPP helpers (VALU cross-lane, per-wave semantics) ----
__device__ __forceinline__ double dpp_shr1_f64(double x) {
    int lo = __double2loint(x), hi = __double2hiint(x);
    int slo = __builtin_amdgcn_update_dpp(0, lo, 0x138, 0xf, 0xf, true);
    int shi = __builtin_amdgcn_update_dpp(0, hi, 0x138, 0xf, 0xf, true);
    return __hiloint2double(shi, slo);   // wave_shr:1, lane0 -> +0.0
}
__device__ __forceinline__ int wave_imax_dpp(int e) {
    e = max(e, __builtin_amdgcn_update_dpp(0, e, 0x111, 0xf, 0xf, true));
    e = max(e, __builtin_amdgcn_update_dpp(0, e, 0x112, 0xf, 0xf, true));
    e = max(e, __builtin_amdgcn_update_dpp(0, e, 0x114, 0xf, 0xf, true));
    e = max(e, __builtin_amdgcn_update_dpp(0, e, 0x118, 0xf, 0xf, true));
    e = max(e, __builtin_amdgcn_update_dpp(0, e, 0x142, 0xf, 0xf, true));
    e = max(e, __builtin_amdgcn_update_dpp(0, e, 0x143, 0xf, 0xf, true));
    return __builtin_amdgcn_readlane(e, 63);
}

// Kernel 1: logits = hs @ W + b, log_softmax over V, probs. Thread-per-row.
__global__ __launch_bounds__(256) void k_logits_softmax(
    const float* __restrict__ hs, const float* __restrict__ W,
    const float* __restrict__ bias, float* __restrict__ logp,
    float* __restrict__ probs)
{
    int r = blockIdx.x * blockDim.x + threadIdx.x;   // row in [0, B*T)
    const float* x = hs + (size_t)r * D_DIM;

    float acc[V_DIM];
#pragma unroll
    for (int v = 0; v < V_DIM; ++v) acc[v] = bias[v];

    for (int k = 0; k < D_DIM; k += 8) {
        float4 xa = *reinterpret_cast<const float4*>(x + k);
        float4 xb = *reinterpret_cast<const float4*>(x + k + 4);
        const float xs[8] = {xa.x, xa.y, xa.z, xa.w, xb.x, xb.y, xb.z, xb.w};
#pragma unroll
        for (int j = 0; j < 8; ++j) {
#pragma unroll
            for (int v = 0; v < V_DIM; ++v)
                acc[v] = fmaf(xs[j], W[(k + j) * V_DIM + v], acc[v]);
        }
    }

    float m = fmaxf(fmaxf(fmaxf(acc[0], acc[1]), fmaxf(acc[2], acc[3])), acc[4]);
    float e[V_DIM];
    float s = 0.f;
#pragma unroll
    for (int v = 0; v < V_DIM; ++v) { e[v] = __expf(acc[v] - m); s += e[v]; }
    float lse = m + __logf(s);
    float inv = 1.f / s;

    size_t base = (size_t)r * V_DIM;
#pragma unroll
    for (int v = 0; v < V_DIM; ++v) {
        logp[base + v]  = acc[v] - lse;
        probs[base + v] = e[v] * inv;
    }
}

// Kernel 2: CTC forward scan, 4-wave skewed pipeline.
// f64 VALU is 1/4-rate (8 cy/wave64 op; r8: 22 ops/step = 176cy matched the
// observed 180), so the single-wave scan was f64-ISSUE-bound. Split the 513
// states over 4 waves (2 states/lane: s0=2gl, s1=2gl+1; ghost 512 on wave3
// lane63). Wave w processes step-block k at iteration i=k+2w (2-block skew):
// the cross-wave boundary value (prev wave lane63's a1) is written to an LDS
// ring at block k and prefetch-read one full barrier-separated iteration
// before use -> LDS latency hidden; ONE __syncthreads per 4 steps.
// Numerics: per-WAVE exact-pow2 frame E (renorm every 16 steps, proven since
// r3); ring entries carry the writer's frame tag; reader rescales by
// v_ldexp_f64 (exact); empty waves adopt the incoming tag; dE>900 flushes
// self to the incoming frame (consumer mass negligible), dE<-1074 underflows
// to 0 via ldexp (incoming negligible) -- both exact-or-negligible.
__global__ __launch_bounds__(256) void k_ctc(
    const float* __restrict__ probs, const int* __restrict__ ys_pad,
    const int* __restrict__ hlens, const int* __restrict__ ys_lens,
    float* __restrict__ nll_out)
{
    __shared__ float  s_probs[T_DIM * V_DIM];                 // f32 staging
    __shared__ __align__(16) double s_pT[V_DIM][TP8];         // f64 [V][T] transposed
    __shared__ double s_alpha[513];
    __shared__ __align__(16) double s_ring[3][8][4];          // boundary ring
    __shared__ int s_rtag[3][8];                              // frame tags
    __shared__ int s_Ew[4];

    const int tid  = threadIdx.x;
    const int w    = tid >> 6;
    const int lane = tid & 63;
    const int gl   = tid;                 // global lane 0..255
    const int b    = blockIdx.x;
    const int hlen = hlens[b];
    const int lb   = ys_lens[b];
    const int Sb   = 2 * lb + 1;
    const float* pb = probs + (size_t)b * T_DIM * V_DIM;
    const int*  yrow = ys_pad + b * L_DIM;

    // ---- stage all T*V probs into LDS (f32), 4 waves in parallel ----
    for (int j = 0; j < (T_DIM * V_DIM) / 256; ++j) {
        __builtin_amdgcn_global_load_lds((gas_fp)(pb + j * 256 + tid),
                                         (las_fp)(&s_probs[j * 256 + w * 64]), 4, 0, 0);
    }
    asm volatile("s_waitcnt vmcnt(0)" ::: "memory");
    __syncthreads();

    // ---- transpose + widen: s_pT[v][t+3] (block k starts at idx 4+4k, 16B aligned) ----
    for (int t = tid; t < T_DIM; t += 256) {
        const float* sp = &s_probs[t * 5];
        s_pT[0][t + 3] = (double)sp[0];
        s_pT[1][t + 3] = (double)sp[1];
        s_pT[2][t + 3] = (double)sp[2];
        s_pT[3][t + 3] = (double)sp[3];
        s_pT[4][t + 3] = (double)sp[4];
    }
    __syncthreads();

    // per-lane labels: state s1=2gl+1 has label yrow[gl]
    const int y  = yrow[gl];
    const int ym = (gl > 0) ? yrow[gl - 1] : -1;
    const double sk = ((gl > 0) && (y != ym)) ? 1.0 : 0.0;
    const bool v0 = (2 * gl)     < Sb;
    const bool v1 = (2 * gl + 1) < Sb;
    const bool vg = (Sb == 513);          // ghost valid only if lb==256

    double a0 = 0.0, a1 = 0.0, g = 0.0;
    if (gl == 0) { a0 = (double)s_probs[0]; a1 = (double)s_probs[y]; }
    int E = 0;                 // wave-uniform frame exponent (exact)
    bool has_mass = (w == 0);

    const int NS = hlen - 1, nblk = NS >> 2, rem = NS & 3;
    const int niter = nblk + 7;

    const double* Pbl = &s_pT[0][0];
    const double* Py  = &s_pT[y][0];

#define LD4(d, p)                                                         \
    { double2 u0_ = *(const double2*)(p);                                 \
      double2 u1_ = *(const double2*)((p) + 2);                           \
      d[0] = u0_.x; d[1] = u0_.y; d[2] = u1_.x; d[3] = u1_.y; }

    double cbl[4], cy4[4], cbnd[4];
    int ctag = 0;
    cbnd[0] = cbnd[1] = cbnd[2] = cbnd[3] = 0.0;
    if (w == 0) { LD4(cbl, Pbl + 4); LD4(cy4, Py + 4); }   // block 0 preload

#define STEPB(s_, WR)                                                     \
    {                                                                     \
        double pdpp_ = dpp_shr1_f64(a1);                                  \
        double px_ = (lane == 0) ? cbnd[s_] : pdpp_;                      \
        if (w == 3) g = (g + a1) * cbl[s_];                               \
        double t1_ = fma(sk, px_, a1 + a0) * cy4[s_];                     \
        a0 = (a0 + px_) * cbl[s_];                                        \
        a1 = t1_;                                                         \
        if (WR && w < 3 && lane == 63) s_ring[w][k & 7][(s_) + 1] = a1;   \
    }

    for (int i = 0; i < niter; ++i) {
        const int k = i - 2 * w;
        const bool fullb = (k >= 0) && (k < nblk);
        const int nst = fullb ? 4 : ((k == nblk && rem > 0) ? rem : 0);

        if (nst) {
            if (w > 0) {
                if (!has_mass) E = ctag;
                int dE = ctag - E;
                if (dE > 900) {     // consumer mass negligible vs incoming
                    a0 = ldexp(a0, -dE); a1 = ldexp(a1, -dE); g = ldexp(g, -dE);
                    E = ctag; dE = 0;
                }
                cbnd[0] = ldexp(cbnd[0], dE); cbnd[1] = ldexp(cbnd[1], dE);
                cbnd[2] = ldexp(cbnd[2], dE); cbnd[3] = ldexp(cbnd[3], dE);
                has_mass = has_mass || (cbnd[0] != 0.0) || (cbnd[1] != 0.0)
                                    || (cbnd[2] != 0.0) || (cbnd[3] != 0.0);
            }
            // block-start boundary publish: a1 = state 128w+127 at t=4k,
            // in the CURRENT frame (tag and all 4 slot values share it).
            if (w < 3 && lane == 63) {
                s_rtag[w][k & 7] = E;
                s_ring[w][k & 7][0] = a1;
            }
            if (nst == 4) {
                STEPB(0, 1) STEPB(1, 1) STEPB(2, 1) STEPB(3, 0)
                if ((k & 3) == 3) {   // renorm every 4 wave-local blocks
                    double m_ = fmax(v0 ? a0 : 0.0, v1 ? a1 : 0.0);
                    if (w == 3 && lane == 63) m_ = fmax(m_, vg ? g : 0.0);
                    int em_ = wave_imax_dpp((__double2hiint(m_) >> 20) & 0x7ff);
                    if (em_ > 0) {
                        double sc_ = __hiloint2double((2046 - em_) << 20, 0);
                        a0 = v0 ? a0 * sc_ : 0.0;
                        a1 = v1 ? a1 * sc_ : 0.0;
                        if (w == 3) g = vg ? g * sc_ : 0.0;
                        E += em_ - 1023;
                    } else {
                        if (!v0) a0 = 0.0;
                        if (!v1) a1 = 0.0;
                        if (w == 3 && !vg) g = 0.0;
                    }
                }
            } else {
                if (nst > 0) STEPB(0, 1)
                if (nst > 1) STEPB(1, 1)
                if (nst > 2) STEPB(2, 1)
            }
        }

        // prefetch next block's probs + boundary (written >=1 iter ago)
        const int kn = k + 1;
        if (kn >= 0 && kn <= nblk) {
            const int off = 4 + 4 * kn;
            LD4(cbl, Pbl + off);
            LD4(cy4, Py + off);
            if (w > 0) {
                LD4(cbnd, &s_ring[w - 1][kn & 7][0]);
                ctag = s_rtag[w - 1][kn & 7];
            }
        }
        __syncthreads();
    }
#undef STEPB
#undef LD4

    // ---- readout: merge per-wave frames ----
    s_alpha[2 * gl]     = a0;
    s_alpha[2 * gl + 1] = a1;
    if (w == 3 && lane == 63) s_alpha[512] = g;
    if (lane == 0) s_Ew[w] = E;
    __syncthreads();
    if (tid == 0) {
        int i1 = 2 * lb - 1, i2 = 2 * lb;
        int w1 = i1 >> 7; if (w1 > 3) w1 = 3;
        int w2 = i2 >> 7; if (w2 > 3) w2 = 3;
        int E1 = s_Ew[w1], E2 = s_Ew[w2];
        int Em = (E1 > E2) ? E1 : E2;
        double s = ldexp(s_alpha[i1], E1 - Em) + ldexp(s_alpha[i2], E2 - Em);
        double nlld = -(log(s) + (double)Em * LN2D);
        float nll = (float)nlld;
        if (!(nll < 1e8f)) nll = 0.f;   // zero_infinity (covers inf/nan)
        nll_out[b] = nll;
    }
}

// Kernel 3: deterministic reduction of 32 per-sample NLLs -> loss.
__global__ __launch_bounds__(64) void k_finalize(
    const float* __restrict__ nll, float* __restrict__ out)
{
    int tid = threadIdx.x;
    float v = (tid < B_DIM) ? nll[tid] : 0.f;
#pragma unroll
    for (int off = 32; off; off >>= 1) v += __shfl_down(v, off, 64);
    if (tid == 0) out[0] = v / (float)B_DIM;
}

extern "C" void kernel_launch(void* const* d_in, const int* in_sizes, int n_in,
                              void* d_out, int out_size, void* d_ws, size_t ws_size,
                              hipStream_t stream) {
    const float* hs      = (const float*)d_in[0];
    const float* W       = (const float*)d_in[1];
    const float* bias    = (const float*)d_in[2];
    const int*   hlens   = (const int*)d_in[3];
    const int*   ys_pad  = (const int*)d_in[4];
    const int*   ys_lens = (const int*)d_in[5];

    float* out   = (float*)d_out;
    float* logp  = out + 1;                                      // (B,T,V) log-softmax
    float* probs = out + 1 + (size_t)B_DIM * T_DIM * V_DIM;      // (B,T,V) softmax
    float* nll   = (float*)d_ws;                                 // 32 floats

    hipLaunchKernelGGL(k_logits_softmax, dim3(B_DIM * T_DIM / 256), dim3(256), 0, stream,
                       hs, W, bias, logp, probs);
    hipLaunchKernelGGL(k_ctc, dim3(B_DIM), dim3(256), 0, stream,
                       probs, ys_pad, hlens, ys_lens, nll);
    hipLaunchKernelGGL(k_finalize, dim3(1), dim3(64), 0, stream, nll, out);
}

// Round 10
// 282.147 us; speedup vs baseline: 1.1330x; 1.1330x over previous
//
#include <hip/hip_runtime.h>
#include <math.h>

#define B_DIM 32
#define T_DIM 2048
#define D_DIM 512
#define V_DIM 5
#define L_DIM 256
#define LN2D 0.6931471805599453
#define TP (T_DIM + 8)

typedef const float __attribute__((address_space(1)))* gas_fp;
typedef float __attribute__((address_space(3)))* las_fp;

// ---- DPP helpers (VALU cross-lane, per-wave semantics) ----
__device__ __forceinline__ double dpp_shr1_f64(double x) {
    int lo = __double2loint(x), hi = __double2hiint(x);
    int slo = __builtin_amdgcn_update_dpp(0, lo, 0x138, 0xf, 0xf, true);
    int shi = __builtin_amdgcn_update_dpp(0, hi, 0x138, 0xf, 0xf, true);
    return __hiloint2double(shi, slo);   // wave_shr:1, lane0 -> +0.0
}
__device__ __forceinline__ int wave_imax_dpp(int e) {
    e = max(e, __builtin_amdgcn_update_dpp(0, e, 0x111, 0xf, 0xf, true));
    e = max(e, __builtin_amdgcn_update_dpp(0, e, 0x112, 0xf, 0xf, true));
    e = max(e, __builtin_amdgcn_update_dpp(0, e, 0x114, 0xf, 0xf, true));
    e = max(e, __builtin_amdgcn_update_dpp(0, e, 0x118, 0xf, 0xf, true));
    e = max(e, __builtin_amdgcn_update_dpp(0, e, 0x142, 0xf, 0xf, true));
    e = max(e, __builtin_amdgcn_update_dpp(0, e, 0x143, 0xf, 0xf, true));
    return __builtin_amdgcn_readlane(e, 63);
}

// Kernel 1: logits = hs @ W + b, log_softmax over V, probs. Thread-per-row.
__global__ __launch_bounds__(256) void k_logits_softmax(
    const float* __restrict__ hs, const float* __restrict__ W,
    const float* __restrict__ bias, float* __restrict__ logp,
    float* __restrict__ probs)
{
    int r = blockIdx.x * blockDim.x + threadIdx.x;   // row in [0, B*T)
    const float* x = hs + (size_t)r * D_DIM;

    float acc[V_DIM];
#pragma unroll
    for (int v = 0; v < V_DIM; ++v) acc[v] = bias[v];

    for (int k = 0; k < D_DIM; k += 8) {
        float4 xa = *reinterpret_cast<const float4*>(x + k);
        float4 xb = *reinterpret_cast<const float4*>(x + k + 4);
        const float xs[8] = {xa.x, xa.y, xa.z, xa.w, xb.x, xb.y, xb.z, xb.w};
#pragma unroll
        for (int j = 0; j < 8; ++j) {
#pragma unroll
            for (int v = 0; v < V_DIM; ++v)
                acc[v] = fmaf(xs[j], W[(k + j) * V_DIM + v], acc[v]);
        }
    }

    float m = fmaxf(fmaxf(fmaxf(acc[0], acc[1]), fmaxf(acc[2], acc[3])), acc[4]);
    float e[V_DIM];
    float s = 0.f;
#pragma unroll
    for (int v = 0; v < V_DIM; ++v) { e[v] = __expf(acc[v] - m); s += e[v]; }
    float lse = m + __logf(s);
    float inv = 1.f / s;

    size_t base = (size_t)r * V_DIM;
#pragma unroll
    for (int v = 0; v < V_DIM; ++v) {
        logp[base + v]  = acc[v] - lse;
        probs[base + v] = e[v] * inv;
    }
}

// Kernel 2: CTC forward scan, 2-wave producer/consumer, BARRIER-FREE.
// f64 linear-prob, per-wave exact-pow2 frames (r9-proven tag/adopt logic).
// wave0: states 0..255 (4/lane), wave1: 256..512 (4/lane + ghost on lane63).
// wave0 streams boundary alpha_t[255] into a full-length LDS array (no ring
// laps) with per-block frame tags; progress counter written at the TOP of
// the next block (same-wave LDS ops commit in order -> no waitcnt). wave1
// polls progress with a read issued a block early (latency hidden) and
// rescales entries into its own frame via ldexp (f64 absorbs the 2^±400
// boundary-vs-max spread that killed f32 in r4). r9's barrier-per-4-steps
// cost ~1000cy/iter; this replaces it with a one-way mailbox.
__global__ __launch_bounds__(128) void k_ctc(
    const float* __restrict__ probs, const int* __restrict__ ys_pad,
    const int* __restrict__ hlens, const int* __restrict__ ys_lens,
    float* __restrict__ nll_out)
{
    __shared__ float  s_probs[T_DIM * V_DIM];                 // 40960 B
    __shared__ __align__(16) double s_pT[V_DIM][TP];          // 82240 B
    __shared__ __align__(16) double s_bnd[T_DIM + 8];         // 16448 B
    __shared__ int    s_btag[(T_DIM / 4) + 8];                // 2080 B
    __shared__ double s_alpha[513];                           // 4104 B
    __shared__ int    s_Ew[2];
    __shared__ int    s_prog;

    const int tid  = threadIdx.x;
    const int w    = tid >> 6;
    const int lane = tid & 63;
    const int gl   = tid;                 // global lane 0..127
    const bool W0  = (w == 0), W1 = (w == 1);
    const int b    = blockIdx.x;
    const int hlen = hlens[b];
    const int lb   = ys_lens[b];
    const int Sb   = 2 * lb + 1;
    const float* pb = probs + (size_t)b * T_DIM * V_DIM;
    const int*  yrow = ys_pad + b * L_DIM;

    if (tid == 0) { s_bnd[0] = 0.0; s_prog = 0; }

    // ---- stage probs into LDS (f32), both waves ----
    for (int j = 0; j < (T_DIM * V_DIM) / 128; ++j) {
        __builtin_amdgcn_global_load_lds((gas_fp)(pb + j * 128 + tid),
                                         (las_fp)(&s_probs[j * 128 + w * 64]), 4, 0, 0);
    }
    asm volatile("s_waitcnt vmcnt(0)" ::: "memory");
    __syncthreads();

    // ---- transpose + widen: s_pT[v][t+3]; block k reads idx 4+4k..7+4k ----
    for (int t = tid; t < T_DIM; t += 128) {
        const float* sp = &s_probs[t * 5];
        s_pT[0][t + 3] = (double)sp[0];
        s_pT[1][t + 3] = (double)sp[1];
        s_pT[2][t + 3] = (double)sp[2];
        s_pT[3][t + 3] = (double)sp[3];
        s_pT[4][t + 3] = (double)sp[4];
    }
    __syncthreads();

    // lane owns states 4gl..4gl+3; odd-state labels j0=2gl, j1=2gl+1
    const int j0 = 2 * gl, j1 = j0 + 1;
    const int y_a = yrow[j0], y_b = yrow[j1];
    const double ska = ((j0 > 0) && (y_a != yrow[j0 > 0 ? j0 - 1 : 0])) ? 1.0 : 0.0;
    const double skb = (y_b != y_a) ? 1.0 : 0.0;
    const bool v0 = (4 * gl)     < Sb;
    const bool v1 = (4 * gl + 1) < Sb;
    const bool v2 = (4 * gl + 2) < Sb;
    const bool v3 = (4 * gl + 3) < Sb;
    const bool vg = W1 && (lane == 63) && (Sb == 513);

    double a0 = 0.0, a1 = 0.0, a2 = 0.0, a3 = 0.0, g = 0.0;
    if (gl == 0) { a0 = (double)s_probs[0]; a1 = (double)s_probs[y_a]; }
    int E = 0;
    bool has_mass = W0;

    const double* q_bl = &s_pT[0][0];
    const double* q_ya = &s_pT[y_a][0];
    const double* q_yb = &s_pT[y_b][0];

    const int NS   = hlen - 1;
    const int nblk = NS >> 2;
    const int rem  = NS & 3;
    const int nbt  = nblk + (rem ? 1 : 0);

    double lpA[12], lpB[12];
    double cb0 = 0, cb1 = 0, cb2 = 0, cb3 = 0;
    double raw0 = 0, raw1 = 0, raw2 = 0, raw3 = 0;
    double bs0 = 0, bs1 = 0, bs2 = 0, bs3 = 0;
    int tagA = 0, tagB = 0, pr = 0;

#define LD4(d, p)                                                         \
    { double2 u0_ = *(const double2*)(p);                                 \
      double2 u1_ = *(const double2*)((p) + 2);                           \
      d[0] = u0_.x; d[1] = u0_.y; d[2] = u1_.x; d[3] = u1_.y; }

#define LOADQ(dst, kk)                                                    \
    { const int off_ = 4 + 4 * (kk);                                      \
      double* d0_ = dst; double* d1_ = dst + 4; double* d2_ = dst + 8;    \
      LD4(d0_, q_bl + off_); LD4(d1_, q_ya + off_); LD4(d2_, q_yb + off_); }

#define STEPX(LP, s_)                                                     \
    {                                                                     \
        double px_ = dpp_shr1_f64(a3);                                    \
        if (W1 && lane == 0) px_ = cb##s_;                                \
        const double bl_ = LP[s_];                                        \
        if (W1) g = (g + a3) * bl_;                                       \
        double n0_ = (a0 + px_) * bl_;                                    \
        double n1_ = fma(ska, px_, a1 + a0) * LP[4 + (s_)];               \
        double n2_ = (a2 + a1) * bl_;                                     \
        double n3_ = fma(skb, a1, a3 + a2) * LP[8 + (s_)];                \
        a0 = n0_; a1 = n1_; a2 = n2_; a3 = n3_;                           \
        bs##s_ = a3;                                                      \
    }

#define STEP4(LP) STEPX(LP, 0) STEPX(LP, 1) STEPX(LP, 2) STEPX(LP, 3)

#define PROGTOP(kk)                                                       \
    if (W0 && lane == 63) *(volatile int*)&s_prog = (kk);

#define PUBLISH4(kk)                                                      \
    if (W0 && lane == 63) {                                               \
        s_bnd[4 * (kk) + 1] = bs0; s_bnd[4 * (kk) + 2] = bs1;             \
        s_bnd[4 * (kk) + 3] = bs2; s_bnd[4 * (kk) + 4] = bs3;             \
        s_btag[kk] = E;                                                   \
    }

// rescale prefetched raw entries into this wave's frame (r9-proven logic)
#define CONSUME()                                                         \
    if (W1) {                                                             \
        pr = *(volatile int*)&s_prog;     /* early issue for end-poll */  \
        int dB_ = tagB - E;                                               \
        bool inz_ = (raw0 != 0.0) || (raw1 != 0.0) ||                     \
                    (raw2 != 0.0) || (raw3 != 0.0);                       \
        if (!has_mass && inz_) { E += dB_; dB_ = 0; }                     \
        else if (dB_ > 900) {                                             \
            double f_ = ldexp(1.0, -dB_);                                 \
            a0 *= f_; a1 *= f_; a2 *= f_; a3 *= f_; g *= f_;              \
            E += dB_; dB_ = 0;                                            \
        }                                                                 \
        int dA_ = tagA - E;                                               \
        cb0 = ldexp(raw0, dA_); cb1 = ldexp(raw1, dB_);                   \
        cb2 = ldexp(raw2, dB_); cb3 = ldexp(raw3, dB_);                   \
        has_mass = has_mass || inz_;                                      \
    }

#define PREFETCH(kk)                                                      \
    if (W1 && (kk) < nbt) {                                               \
        volatile int* vp_ = &s_prog;                                      \
        while (pr < (kk) + 1) {                                           \
            pr = *vp_;                                                    \
            if (pr < (kk) + 1) __builtin_amdgcn_s_sleep(2);               \
        }                                                                 \
        __asm__ volatile("" ::: "memory");                                \
        const double* bp_ = &s_bnd[4 * (kk)];                             \
        raw0 = bp_[0]; raw1 = bp_[1]; raw2 = bp_[2]; raw3 = bp_[3];       \
        tagA = ((kk) >= 1) ? s_btag[(kk) - 1] : s_btag[0];                \
        tagB = s_btag[(kk)];                                              \
    }

#define RENORM()                                                          \
    {                                                                     \
        double m_ = fmax(fmax(v0 ? a0 : 0.0, v1 ? a1 : 0.0),              \
                         fmax(v2 ? a2 : 0.0, v3 ? a3 : 0.0));             \
        if (vg) m_ = fmax(m_, g);                                         \
        int em_ = wave_imax_dpp((__double2hiint(m_) >> 20) & 0x7ff);      \
        if (em_ > 0) {                                                    \
            double sc_ = __hiloint2double((2046 - em_) << 20, 0);         \
            a0 = v0 ? a0 * sc_ : 0.0;  a1 = v1 ? a1 * sc_ : 0.0;          \
            a2 = v2 ? a2 * sc_ : 0.0;  a3 = v3 ? a3 * sc_ : 0.0;          \
            if (W1) g = vg ? g * sc_ : 0.0;                               \
            E += em_ - 1023;                                              \
        } else {                                                          \
            if (!v0) a0 = 0.0; if (!v1) a1 = 0.0;                         \
            if (!v2) a2 = 0.0; if (!v3) a3 = 0.0;                         \
            if (W1 && !vg) g = 0.0;                                       \
        }                                                                 \
    }

    LOADQ(lpA, 0);
    // consumer: wait for producer block 0, preload its entries + tag
    if (W1) {
        volatile int* vp = &s_prog;
        pr = *vp;
        while (pr < 1) { __builtin_amdgcn_s_sleep(8); pr = *vp; }
        __asm__ volatile("" ::: "memory");
        raw0 = s_bnd[0]; raw1 = s_bnd[1]; raw2 = s_bnd[2]; raw3 = s_bnd[3];
        tagB = s_btag[0]; tagA = tagB;
    }

    int k = 0;
    for (; k + 2 <= nblk; k += 2) {
        PROGTOP(k); CONSUME();
        LOADQ(lpB, k + 1);
        STEP4(lpA); PUBLISH4(k);
        PREFETCH(k + 1);
        PROGTOP(k + 1); CONSUME();
        if (k + 2 < nbt) LOADQ(lpA, k + 2);
        STEP4(lpB); PUBLISH4(k + 1);
        if (k & 2) RENORM();
        PREFETCH(k + 2);
    }
    if (k < nblk) {                 // leftover full block (probs in lpA)
        PROGTOP(k); CONSUME();
        STEP4(lpA); PUBLISH4(k);
        if ((k & 3) == 3) RENORM();
        PREFETCH(k + 1);
        k++;
    }
    if (rem) {                      // tail block k == nblk, rem steps
        PROGTOP(k); CONSUME();
        LOADQ(lpA, k);
        STEPX(lpA, 0);
        if (rem > 1) STEPX(lpA, 1);
        if (rem > 2) STEPX(lpA, 2);
        if (W0 && lane == 63) {
            s_bnd[4 * k + 1] = bs0;
            if (rem > 1) s_bnd[4 * k + 2] = bs1;
            if (rem > 2) s_bnd[4 * k + 3] = bs2;
            s_btag[k] = E;
        }
    }
    // final publish (one-time hard drain so the last entries are visible)
    if (W0 && lane == 63) {
        __asm__ volatile("s_waitcnt lgkmcnt(0)" ::: "memory");
        *(volatile int*)&s_prog = nbt;
    }

    // ---- readout: merge per-wave frames ----
    s_alpha[4 * gl + 0] = a0;
    s_alpha[4 * gl + 1] = a1;
    s_alpha[4 * gl + 2] = a2;
    s_alpha[4 * gl + 3] = a3;
    if (W1 && lane == 63) s_alpha[512] = g;
    if (lane == 0) s_Ew[w] = E;
    __syncthreads();
    if (tid == 0) {
        int i1 = 2 * lb - 1, i2 = 2 * lb;
        int w1 = i1 >> 8; if (w1 > 1) w1 = 1;
        int w2 = i2 >> 8; if (w2 > 1) w2 = 1;
        int E1 = s_Ew[w1], E2 = s_Ew[w2];
        int Em = (E1 > E2) ? E1 : E2;
        double s = ldexp(s_alpha[i1], E1 - Em) + ldexp(s_alpha[i2], E2 - Em);
        double nlld = -(log(s) + (double)Em * LN2D);
        float nll = (float)nlld;
        if (!(nll < 1e8f)) nll = 0.f;   // zero_infinity (covers inf/nan)
        nll_out[b] = nll;
    }
#undef STEPX
#undef STEP4
#undef LOADQ
#undef LD4
#undef PROGTOP
#undef PUBLISH4
#undef CONSUME
#undef PREFETCH
#undef RENORM
}

// Kernel 3: deterministic reduction of 32 per-sample NLLs -> loss.
__global__ __launch_bounds__(64) void k_finalize(
    const float* __restrict__ nll, float* __restrict__ out)
{
    int tid = threadIdx.x;
    float v = (tid < B_DIM) ? nll[tid] : 0.f;
#pragma unroll
    for (int off = 32; off; off >>= 1) v += __shfl_down(v, off, 64);
    if (tid == 0) out[0] = v / (float)B_DIM;
}

extern "C" void kernel_launch(void* const* d_in, const int* in_sizes, int n_in,
                              void* d_out, int out_size, void* d_ws, size_t ws_size,
                              hipStream_t stream) {
    const float* hs      = (const float*)d_in[0];
    const float* W       = (const float*)d_in[1];
    const float* bias    = (const float*)d_in[2];
    const int*   hlens   = (const int*)d_in[3];
    const int*   ys_pad  = (const int*)d_in[4];
    const int*   ys_lens = (const int*)d_in[5];

    float* out   = (float*)d_out;
    float* logp  = out + 1;                                      // (B,T,V) log-softmax
    float* probs = out + 1 + (size_t)B_DIM * T_DIM * V_DIM;      // (B,T,V) softmax
    float* nll   = (float*)d_ws;                                 // 32 floats

    hipLaunchKernelGGL(k_logits_softmax, dim3(B_DIM * T_DIM / 256), dim3(256), 0, stream,
                       hs, W, bias, logp, probs);
    hipLaunchKernelGGL(k_ctc, dim3(B_DIM), dim3(128), 0, stream,
                       probs, ys_pad, hlens, ys_lens, nll);
    hipLaunchKernelGGL(k_finalize, dim3(1), dim3(64), 0, stream, nll, out);
}

// Round 11
// 143.620 us; speedup vs baseline: 2.2259x; 1.9645x over previous
//
#include <hip/hip_runtime.h>
#include <math.h>

#define B_DIM 32
#define T_DIM 2048
#define D_DIM 512
#define V_DIM 5
#define L_DIM 256
#define LN2D 0.6931471805599453
#define TP (T_DIM + 4)

typedef const float __attribute__((address_space(1)))* gas_fp;
typedef float __attribute__((address_space(3)))* las_fp;

// ---- DPP helpers (VALU cross-lane, no DS pipe) ----
__device__ __forceinline__ double dpp_shr1_f64(double x) {
    int lo = __double2loint(x), hi = __double2hiint(x);
    int slo = __builtin_amdgcn_update_dpp(0, lo, 0x138, 0xf, 0xf, true);
    int shi = __builtin_amdgcn_update_dpp(0, hi, 0x138, 0xf, 0xf, true);
    return __hiloint2double(shi, slo);   // wave_shr:1, lane0 -> +0.0
}
__device__ __forceinline__ int wave_imax_dpp(int e) {
    e = max(e, __builtin_amdgcn_update_dpp(0, e, 0x111, 0xf, 0xf, true));
    e = max(e, __builtin_amdgcn_update_dpp(0, e, 0x112, 0xf, 0xf, true));
    e = max(e, __builtin_amdgcn_update_dpp(0, e, 0x114, 0xf, 0xf, true));
    e = max(e, __builtin_amdgcn_update_dpp(0, e, 0x118, 0xf, 0xf, true));
    e = max(e, __builtin_amdgcn_update_dpp(0, e, 0x142, 0xf, 0xf, true));
    e = max(e, __builtin_amdgcn_update_dpp(0, e, 0x143, 0xf, 0xf, true));
    return __builtin_amdgcn_readlane(e, 63);
}
__device__ __forceinline__ float wave_fsum_dpp(float x) {
    // canonical GCN full-wave sum; total lands in lane 63
    x += __int_as_float(__builtin_amdgcn_update_dpp(0, __float_as_int(x), 0x111, 0xf, 0xf, true));
    x += __int_as_float(__builtin_amdgcn_update_dpp(0, __float_as_int(x), 0x112, 0xf, 0xf, true));
    x += __int_as_float(__builtin_amdgcn_update_dpp(0, __float_as_int(x), 0x114, 0xf, 0xf, true));
    x += __int_as_float(__builtin_amdgcn_update_dpp(0, __float_as_int(x), 0x118, 0xf, 0xf, true));
    x += __int_as_float(__builtin_amdgcn_update_dpp(0, __float_as_int(x), 0x142, 0xa, 0xf, false));
    x += __int_as_float(__builtin_amdgcn_update_dpp(0, __float_as_int(x), 0x143, 0xc, 0xf, false));
    return x;
}

// Kernel 1 (v2): wave-per-row GEMV + softmax. Lane i holds 8 hs elements
// (2 coalesced float4 loads: 1KB per wave per load) and 40 preloaded W
// coefficients; 5 dots via DPP-tree reduce; lane 63 does softmax + stores.
// Replaces thread-per-row (lanes strided 2KB apart -> uncoalesced).
__global__ __launch_bounds__(256) void k_logits_softmax(
    const float* __restrict__ hs, const float* __restrict__ W,
    const float* __restrict__ bias, float* __restrict__ logp,
    float* __restrict__ probs)
{
    const int lane = threadIdx.x & 63;
    const int wid  = (blockIdx.x * blockDim.x + threadIdx.x) >> 6;
    const int nwav = (gridDim.x * blockDim.x) >> 6;

    float wr[2][4][V_DIM];
#pragma unroll
    for (int c = 0; c < 2; ++c)
#pragma unroll
        for (int j = 0; j < 4; ++j) {
            const int k = c * 256 + lane * 4 + j;
#pragma unroll
            for (int v = 0; v < V_DIM; ++v) wr[c][j][v] = W[k * V_DIM + v];
        }
    float br[V_DIM];
#pragma unroll
    for (int v = 0; v < V_DIM; ++v) br[v] = bias[v];

    for (int row = wid; row < B_DIM * T_DIM; row += nwav) {
        const float* x = hs + (size_t)row * D_DIM;
        float4 xa = *reinterpret_cast<const float4*>(x + lane * 4);
        float4 xb = *reinterpret_cast<const float4*>(x + 256 + lane * 4);
        const float xs0[4] = {xa.x, xa.y, xa.z, xa.w};
        const float xs1[4] = {xb.x, xb.y, xb.z, xb.w};

        float acc[V_DIM];
#pragma unroll
        for (int v = 0; v < V_DIM; ++v) acc[v] = 0.f;
#pragma unroll
        for (int j = 0; j < 4; ++j)
#pragma unroll
            for (int v = 0; v < V_DIM; ++v) {
                acc[v] = fmaf(xs0[j], wr[0][j][v], acc[v]);
                acc[v] = fmaf(xs1[j], wr[1][j][v], acc[v]);
            }
#pragma unroll
        for (int v = 0; v < V_DIM; ++v) acc[v] = wave_fsum_dpp(acc[v]);

        if (lane == 63) {
#pragma unroll
            for (int v = 0; v < V_DIM; ++v) acc[v] += br[v];
            float m = fmaxf(fmaxf(fmaxf(acc[0], acc[1]), fmaxf(acc[2], acc[3])), acc[4]);
            float e[V_DIM], s = 0.f;
#pragma unroll
            for (int v = 0; v < V_DIM; ++v) { e[v] = __expf(acc[v] - m); s += e[v]; }
            float lse = m + __logf(s);
            float inv = 1.f / s;
            size_t base = (size_t)row * V_DIM;
#pragma unroll
            for (int v = 0; v < V_DIM; ++v) {
                logp[base + v]  = acc[v] - lse;
                probs[base + v] = e[v] * inv;
            }
        }
    }
}

// Kernel 2: CTC forward scan, BLANK-NORMALIZED f64 (beta = alpha / prod pb),
// single wave, single global exact-pow2 frame (r3/5/8-proven numerics).
// Even (blank) states lose their multiply: pure adds. Odd states multiply by
// staged r_t[y] = p_t[y]/p_t[blank]. 17 f64 ops/step (was 22; f64 pipe is
// per-CU shared per r8/r9/r10 evidence, so op count is the only lever).
// NLL adds back sum(log pb) accumulated at staging (frexpf + __log2f, f64
// accum, ~2e-4 abs). Renorm every 16 steps; max via u32 hi-word compare
// (monotone for positive doubles); invalid states excluded from max but NOT
// zeroed (deps are upward-only; drift bounded ~2^±100 -> no inf).
__global__ __launch_bounds__(64) void k_ctc(
    const float* __restrict__ probs, const int* __restrict__ ys_pad,
    const int* __restrict__ hlens, const int* __restrict__ ys_lens,
    float* __restrict__ nll_out)
{
    __shared__ float  s_probs[T_DIM * V_DIM];                // f32 staging
    __shared__ __align__(16) double s_pT[4][TP];             // r ratios, [label-1][t+3]
    __shared__ double s_alpha[513];
    __shared__ double s_red[64];

    const int b    = blockIdx.x;
    const int lane = threadIdx.x;        // 0..63
    const int hlen = hlens[b];
    const int lb   = ys_lens[b];
    const int Sb   = 2 * lb + 1;
    const float* pb = probs + (size_t)b * T_DIM * V_DIM;
    const int*  yrow = ys_pad + b * L_DIM;

    // ---- stage all T*V probs into LDS (f32) ----
    for (int i = 0; i < (T_DIM * V_DIM) / 64; ++i) {
        __builtin_amdgcn_global_load_lds((gas_fp)(pb + i * 64 + lane),
                                         (las_fp)(&s_probs[i * 64]), 4, 0, 0);
    }
    asm volatile("s_waitcnt vmcnt(0)" ::: "memory");

    // ---- transpose: r ratios to f64 [label][t], + sum log2(p_blank) ----
    // single wave: per-wave in-order LDS, no barrier needed
    double lg2 = 0.0;
    for (int i = 0; i < T_DIM / 64; ++i) {
        const int t = i * 64 + lane;
        const float* sp = &s_probs[t * 5];
        const float p0 = sp[0];
        const float inv = 1.0f / p0;
        s_pT[0][t + 3] = (double)(sp[1] * inv);
        s_pT[1][t + 3] = (double)(sp[2] * inv);
        s_pT[2][t + 3] = (double)(sp[3] * inv);
        s_pT[3][t + 3] = (double)(sp[4] * inv);
        if (t < hlen) {
            int ee; float mm = frexpf(p0, &ee);
            lg2 += (double)ee + (double)__log2f(mm);
        }
    }

    // labels for this lane's 4 odd states (8l+{1,3,5,7} -> labels 4l..4l+3)
    const int y0 = yrow[4 * lane + 0];
    const int y1 = yrow[4 * lane + 1];
    const int y2 = yrow[4 * lane + 2];
    const int y3 = yrow[4 * lane + 3];
    const int ym1 = (lane > 0) ? yrow[4 * lane - 1] : -1;

    const double sk0 = ((lane > 0) && (y0 != ym1)) ? 1.0 : 0.0;
    const double sk1 = (y1 != y0) ? 1.0 : 0.0;
    const double sk2 = (y2 != y1) ? 1.0 : 0.0;
    const double sk3 = (y3 != y2) ? 1.0 : 0.0;

    bool vmask[9];
#pragma unroll
    for (int i = 0; i < 9; ++i) vmask[i] = (8 * lane + i) < Sb;

    double aA[9], aB[9];
#pragma unroll
    for (int i = 0; i < 9; ++i) aA[i] = 0.0;
    if (lane == 0) {
        aA[0] = 1.0;                     // beta_0[0] = pb/pb
        aA[1] = s_pT[y0 - 1][3];         // beta_0[1] = r_0[y0]
    }
    int E = 0;   // global (wave-uniform) base-2 exponent, exact

    const double* q_y0 = &s_pT[y0 - 1][0];
    const double* q_y1 = &s_pT[y1 - 1][0];
    const double* q_y2 = &s_pT[y2 - 1][0];
    const double* q_y3 = &s_pT[y3 - 1][0];

#define LD4(d, p)                                                         \
    { double2 u0_ = *(const double2*)(p);                                 \
      double2 u1_ = *(const double2*)((p) + 2);                           \
      (d)[0] = u0_.x; (d)[1] = u0_.y; (d)[2] = u1_.x; (d)[3] = u1_.y; }

#define LOADQ(dst, kk)                                                    \
    { const int off_ = 4 + 4 * (kk);                                      \
      LD4(dst + 0,  q_y0 + off_); LD4(dst + 4,  q_y1 + off_);             \
      LD4(dst + 8,  q_y2 + off_); LD4(dst + 12, q_y3 + off_); }

// blank-normalized step: evens pure adds, odds (add,fma,mul r). DPP shift
// at top (4cy, consumed ~8 f64 ops later).
#define STEPX(O, N, L, s_)                                                \
    {                                                                     \
        double p7_ = dpp_shr1_f64(O[7]);                                  \
        N[7] = fma(sk3, O[5], O[7] + O[6]) * L[12 + (s_)];                \
        N[2] = O[2] + O[1];                                               \
        N[3] = fma(sk1, O[1], O[3] + O[2]) * L[4 + (s_)];                 \
        N[4] = O[4] + O[3];                                               \
        N[5] = fma(sk2, O[3], O[5] + O[4]) * L[8 + (s_)];                 \
        N[6] = O[6] + O[5];                                               \
        N[8] = O[8] + O[7];                                               \
        N[0] = O[0] + p7_;                                                \
        N[1] = fma(sk0, p7_, O[1] + O[0]) * L[0 + (s_)];                  \
    }

#define STEP4(L)                                                          \
    STEPX(aA, aB, L, 0); STEPX(aB, aA, L, 1);                             \
    STEPX(aA, aB, L, 2); STEPX(aB, aA, L, 3);

// Exact pow2 renorm: u32 compare on hi-words (monotone for positive f64);
// invalid states excluded from max, scaled but never zeroed.
#define RENORM()                                                          \
    {                                                                     \
        int hm_ = 0;                                                      \
        _Pragma("unroll")                                                 \
        for (int i_ = 0; i_ < 9; ++i_) {                                  \
            int h_ = __double2hiint(aA[i_]);                              \
            hm_ = vmask[i_] ? max(hm_, h_) : hm_;                         \
        }                                                                 \
        int em_ = wave_imax_dpp(hm_) >> 20;                               \
        if (em_ > 0) {                                                    \
            double sc_ = __hiloint2double((2046 - em_) << 20, 0);         \
            _Pragma("unroll")                                             \
            for (int i_ = 0; i_ < 9; ++i_) aA[i_] *= sc_;                 \
            E += em_ - 1023;                                              \
        }                                                                 \
    }

    const int NS = hlen - 1;       // steps t = 1..NS
    const int nfull = NS >> 2;     // full 4-step blocks
    double lpA[16], lpB[16];
    LOADQ(lpA, 0);                 // block 0 (t=1..4)

    int blk = 0;
    for (; blk + 2 <= nfull; blk += 2) {
        LOADQ(lpB, blk + 1);
        STEP4(lpA);
        LOADQ(lpA, blk + 2);
        STEP4(lpB);
        if (blk & 2) RENORM();     // every 16 steps (f64 headroom ample)
    }
    if (blk < nfull) {             // leftover full block, data in lpA
        STEP4(lpA);
    }
    // tail steps (0..3): t = 4*nfull+1 .. NS
    for (int tt = 4 * nfull + 1; tt <= NS; ++tt) {
        double lt[16];
        lt[0]  = s_pT[y0 - 1][tt + 3];
        lt[4]  = s_pT[y1 - 1][tt + 3];
        lt[8]  = s_pT[y2 - 1][tt + 3];
        lt[12] = s_pT[y3 - 1][tt + 3];
        STEPX(aA, aB, lt, 0);
#pragma unroll
        for (int i = 0; i < 9; ++i) aA[i] = aB[i];
    }

    // ---- readout ----
#pragma unroll
    for (int i = 0; i < 8; ++i) s_alpha[8 * lane + i] = aA[i];
    if (lane == 63) s_alpha[512] = aA[8];
    s_red[lane] = lg2;
    __syncthreads();
    if (lane == 0) {
        double lg2tot = 0.0;
        for (int i = 0; i < 64; ++i) lg2tot += s_red[i];
        int i1 = 2 * lb - 1;
        double s = s_alpha[i1] + s_alpha[i1 + 1];
        double nlld = -(log(s) + ((double)E + lg2tot) * LN2D);
        float nll = (float)nlld;
        if (!(nll < 1e8f)) nll = 0.f;   // zero_infinity (covers inf/nan)
        nll_out[b] = nll;
    }
#undef STEPX
#undef STEP4
#undef LOADQ
#undef LD4
#undef RENORM
}

// Kernel 3: deterministic reduction of 32 per-sample NLLs -> loss.
__global__ __launch_bounds__(64) void k_finalize(
    const float* __restrict__ nll, float* __restrict__ out)
{
    int tid = threadIdx.x;
    float v = (tid < B_DIM) ? nll[tid] : 0.f;
#pragma unroll
    for (int off = 32; off; off >>= 1) v += __shfl_down(v, off, 64);
    if (tid == 0) out[0] = v / (float)B_DIM;
}

extern "C" void kernel_launch(void* const* d_in, const int* in_sizes, int n_in,
                              void* d_out, int out_size, void* d_ws, size_t ws_size,
                              hipStream_t stream) {
    const float* hs      = (const float*)d_in[0];
    const float* W       = (const float*)d_in[1];
    const float* bias    = (const float*)d_in[2];
    const int*   hlens   = (const int*)d_in[3];
    const int*   ys_pad  = (const int*)d_in[4];
    const int*   ys_lens = (const int*)d_in[5];

    float* out   = (float*)d_out;
    float* logp  = out + 1;                                      // (B,T,V) log-softmax
    float* probs = out + 1 + (size_t)B_DIM * T_DIM * V_DIM;      // (B,T,V) softmax
    float* nll   = (float*)d_ws;                                 // 32 floats

    hipLaunchKernelGGL(k_logits_softmax, dim3(1024), dim3(256), 0, stream,
                       hs, W, bias, logp, probs);
    hipLaunchKernelGGL(k_ctc, dim3(B_DIM), dim3(64), 0, stream,
                       probs, ys_pad, hlens, ys_lens, nll);
    hipLaunchKernelGGL(k_finalize, dim3(1), dim3(64), 0, stream, nll, out);
}

// Round 13
// 143.586 us; speedup vs baseline: 2.2264x; 1.0002x over previous
//
#include <hip/hip_runtime.h>
#include <math.h>

#define B_DIM 32
#define T_DIM 2048
#define D_DIM 512
#define V_DIM 5
#define L_DIM 256
#define LN2D 0.6931471805599453
#define TP (T_DIM + 4)

typedef const float __attribute__((address_space(1)))* gas_fp;
typedef float __attribute__((address_space(3)))* las_fp;

// ---- DPP helpers (VALU cross-lane, no DS pipe) ----
__device__ __forceinline__ float dpp_shr1_f32(float x) {
    return __int_as_float(__builtin_amdgcn_update_dpp(
        0, __float_as_int(x), 0x138, 0xf, 0xf, true));  // wave_shr:1, lane0->0
}
__device__ __forceinline__ int dpp_shr1_i32(int x) {
    return __builtin_amdgcn_update_dpp(0, x, 0x138, 0xf, 0xf, true);
}
__device__ __forceinline__ float wave_fsum_dpp(float x) {
    // canonical GCN full-wave sum; total lands in lane 63
    x += __int_as_float(__builtin_amdgcn_update_dpp(0, __float_as_int(x), 0x111, 0xf, 0xf, true));
    x += __int_as_float(__builtin_amdgcn_update_dpp(0, __float_as_int(x), 0x112, 0xf, 0xf, true));
    x += __int_as_float(__builtin_amdgcn_update_dpp(0, __float_as_int(x), 0x114, 0xf, 0xf, true));
    x += __int_as_float(__builtin_amdgcn_update_dpp(0, __float_as_int(x), 0x118, 0xf, 0xf, true));
    x += __int_as_float(__builtin_amdgcn_update_dpp(0, __float_as_int(x), 0x142, 0xa, 0xf, false));
    x += __int_as_float(__builtin_amdgcn_update_dpp(0, __float_as_int(x), 0x143, 0xc, 0xf, false));
    return x;
}

// Kernel 1: wave-per-row GEMV + softmax (coalesced; r11-proven).
__global__ __launch_bounds__(256) void k_logits_softmax(
    const float* __restrict__ hs, const float* __restrict__ W,
    const float* __restrict__ bias, float* __restrict__ logp,
    float* __restrict__ probs)
{
    const int lane = threadIdx.x & 63;
    const int wid  = (blockIdx.x * blockDim.x + threadIdx.x) >> 6;
    const int nwav = (gridDim.x * blockDim.x) >> 6;

    float wr[2][4][V_DIM];
#pragma unroll
    for (int c = 0; c < 2; ++c)
#pragma unroll
        for (int j = 0; j < 4; ++j) {
            const int k = c * 256 + lane * 4 + j;
#pragma unroll
            for (int v = 0; v < V_DIM; ++v) wr[c][j][v] = W[k * V_DIM + v];
        }
    float br[V_DIM];
#pragma unroll
    for (int v = 0; v < V_DIM; ++v) br[v] = bias[v];

    for (int row = wid; row < B_DIM * T_DIM; row += nwav) {
        const float* x = hs + (size_t)row * D_DIM;
        float4 xa = *reinterpret_cast<const float4*>(x + lane * 4);
        float4 xb = *reinterpret_cast<const float4*>(x + 256 + lane * 4);
        const float xs0[4] = {xa.x, xa.y, xa.z, xa.w};
        const float xs1[4] = {xb.x, xb.y, xb.z, xb.w};

        float acc[V_DIM];
#pragma unroll
        for (int v = 0; v < V_DIM; ++v) acc[v] = 0.f;
#pragma unroll
        for (int j = 0; j < 4; ++j)
#pragma unroll
            for (int v = 0; v < V_DIM; ++v) {
                acc[v] = fmaf(xs0[j], wr[0][j][v], acc[v]);
                acc[v] = fmaf(xs1[j], wr[1][j][v], acc[v]);
            }
#pragma unroll
        for (int v = 0; v < V_DIM; ++v) acc[v] = wave_fsum_dpp(acc[v]);

        if (lane == 63) {
#pragma unroll
            for (int v = 0; v < V_DIM; ++v) acc[v] += br[v];
            float m = fmaxf(fmaxf(fmaxf(acc[0], acc[1]), fmaxf(acc[2], acc[3])), acc[4]);
            float e[V_DIM], s = 0.f;
#pragma unroll
            for (int v = 0; v < V_DIM; ++v) { e[v] = __expf(acc[v] - m); s += e[v]; }
            float lse = m + __logf(s);
            float inv = 1.f / s;
            size_t base = (size_t)row * V_DIM;
#pragma unroll
            for (int v = 0; v < V_DIM; ++v) {
                logp[base + v]  = acc[v] - lse;
                probs[base + v] = e[v] * inv;
            }
        }
    }
}

// Kernel 2: CTC forward scan — blank-normalized F32 per-lane BFP, r12 + 3
// structural fixes for the NaN cascade r12 hit (absmax 1656 = all-zeroed):
// (1) ADOPT-ON-THRESHOLD + ZERO: lanes with max < 1e-12 (~2^-40, negligible
//     by construction) adopt upstream E-32 and ZERO their values. r12's
//     `== 0` test let tiny junk freeze a lane's frame while upstream E
//     climbed -> delta ran away -> ldexpf -> inf. Also auto-flushes
//     fully-invalid lanes every window (no inf there either).
// (2) SATURATING SCALE: em clamped to 253 before encoding 2^(127-em); r12
//     produced sc=0 at em=254 and sc=-inf at em=255 (inf) -> NaN.
// (3) DELTA CLAMP [-126, +52]: inactive in normal operation (steady delta
//     -20..+44), guards pathological streaks.
// Frame math otherwise exact pow2 (r3-r11 lineage); renorm every 8 steps
// (window growth typ 2^12, worst 2^53; injected <= 2^(13+52) no inf).
__global__ __launch_bounds__(64) void k_ctc(
    const float* __restrict__ probs, const int* __restrict__ ys_pad,
    const int* __restrict__ hlens, const int* __restrict__ ys_lens,
    float* __restrict__ nll_out)
{
    __shared__ float  s_probs[T_DIM * V_DIM];               // f32 staging
    __shared__ __align__(16) float s_pT[4][TP];             // ratios [label-1][t+3]
    __shared__ float  s_beta[513];
    __shared__ int    s_E[64];
    __shared__ double s_red[64];

    const int b    = blockIdx.x;
    const int lane = threadIdx.x;        // 0..63
    const int hlen = hlens[b];
    const int lb   = ys_lens[b];
    const int Sb   = 2 * lb + 1;
    const float* pb = probs + (size_t)b * T_DIM * V_DIM;
    const int*  yrow = ys_pad + b * L_DIM;

    // ---- stage all T*V probs into LDS (f32) ----
    for (int i = 0; i < (T_DIM * V_DIM) / 64; ++i) {
        __builtin_amdgcn_global_load_lds((gas_fp)(pb + i * 64 + lane),
                                         (las_fp)(&s_probs[i * 64]), 4, 0, 0);
    }
    asm volatile("s_waitcnt vmcnt(0)" ::: "memory");

    // ---- transpose: blank-ratios r_t[y]=p_t[y]/p_t[blank] + sum log2(pb) ----
    double lg2 = 0.0;
    for (int i = 0; i < T_DIM / 64; ++i) {
        const int t = i * 64 + lane;
        const float* sp = &s_probs[t * 5];
        const float p0 = sp[0];
        const float inv = 1.0f / p0;
        s_pT[0][t + 3] = sp[1] * inv;
        s_pT[1][t + 3] = sp[2] * inv;
        s_pT[2][t + 3] = sp[3] * inv;
        s_pT[3][t + 3] = sp[4] * inv;
        if (t < hlen) {
            int ee; float mm = frexpf(p0, &ee);
            lg2 += (double)ee + (double)__log2f(mm);
        }
    }

    // labels for this lane's 4 odd states (8l+{1,3,5,7} -> labels 4l..4l+3)
    const int y0 = yrow[4 * lane + 0];
    const int y1 = yrow[4 * lane + 1];
    const int y2 = yrow[4 * lane + 2];
    const int y3 = yrow[4 * lane + 3];
    const int ym1 = (lane > 0) ? yrow[4 * lane - 1] : -1;

    const float sk0 = ((lane > 0) && (y0 != ym1)) ? 1.f : 0.f;
    const float sk1 = (y1 != y0) ? 1.f : 0.f;
    const float sk2 = (y2 != y1) ? 1.f : 0.f;
    const float sk3 = (y3 != y2) ? 1.f : 0.f;

    bool vmask[9];
#pragma unroll
    for (int i = 0; i < 9; ++i) vmask[i] = (8 * lane + i) < Sb;

    float aA[9], aB[9];
#pragma unroll
    for (int i = 0; i < 9; ++i) aA[i] = 0.f;
    if (lane == 0) {
        aA[0] = 1.f;                     // beta_0[0]
        aA[1] = s_pT[y0 - 1][3];         // beta_0[1] = r_0[y0]
    }
    int E = 0;       // per-LANE frame exponent (true = rel * 2^E)
    int delta = 0;   // E_{lane-1} - E_lane, refreshed each renorm

    const float* q_y0 = &s_pT[y0 - 1][0];
    const float* q_y1 = &s_pT[y1 - 1][0];
    const float* q_y2 = &s_pT[y2 - 1][0];
    const float* q_y3 = &s_pT[y3 - 1][0];

#define LD4F(d, p)                                                        \
    { float4 u_ = *(const float4*)(p);                                    \
      (d)[0] = u_.x; (d)[1] = u_.y; (d)[2] = u_.z; (d)[3] = u_.w; }

#define LOADQ(dst, kk)                                                    \
    { const int off_ = 4 + 4 * (kk);                                      \
      LD4F(dst + 0,  q_y0 + off_); LD4F(dst + 4,  q_y1 + off_);           \
      LD4F(dst + 8,  q_y2 + off_); LD4F(dst + 12, q_y3 + off_); }

// blank-normalized f32 step; dpp+ldexp issued at top, consumed at end.
#define STEPX(O, N, L, s_)                                                \
    {                                                                     \
        float p7_ = ldexpf(dpp_shr1_f32(O[7]), delta);                    \
        N[7] = fmaf(sk3, O[5], O[7] + O[6]) * L[12 + (s_)];               \
        N[2] = O[2] + O[1];                                               \
        N[3] = fmaf(sk1, O[1], O[3] + O[2]) * L[4 + (s_)];                \
        N[4] = O[4] + O[3];                                               \
        N[5] = fmaf(sk2, O[3], O[5] + O[4]) * L[8 + (s_)];                \
        N[6] = O[6] + O[5];                                               \
        N[8] = O[8] + O[7];                                               \
        N[0] = O[0] + p7_;                                                \
        N[1] = fmaf(sk0, p7_, O[1] + O[0]) * L[0 + (s_)];                 \
    }

#define STEP4(L)                                                          \
    STEPX(aA, aB, L, 0); STEPX(aB, aA, L, 1);                             \
    STEPX(aA, aB, L, 2); STEPX(aB, aA, L, 3);

// Per-lane exact-pow2 renorm (every 8 steps), divergence-free.
// real mass (m >= 2^-40): scale so max -> ~[1,2), E += em-127 (exact).
// else: ZERO the lane and adopt upstream E-32 (junk <= 2^-40 of own frame
// is negligible; zeroing keeps value/frame consistent). Saturating scale
// encoding (em clamped to 253) and delta clamp close r12's inf/NaN holes.
#define RENORM()                                                          \
    {                                                                     \
        float m_ = 0.f;                                                   \
        _Pragma("unroll")                                                 \
        for (int i_ = 0; i_ < 9; ++i_)                                    \
            m_ = vmask[i_] ? fmaxf(m_, aA[i_]) : m_;                      \
        const bool big_ = (m_ >= 1e-12f);                                 \
        int em_ = (__float_as_int(m_) >> 23) & 0xff;                      \
        em_ = em_ > 253 ? 253 : em_;                                      \
        const float sc_ = __int_as_float((254 - (big_ ? em_ : 127)) << 23); \
        _Pragma("unroll")                                                 \
        for (int i_ = 0; i_ < 9; ++i_)                                    \
            aA[i_] = big_ ? aA[i_] * sc_ : 0.f;                           \
        const int En_ = E + (big_ ? em_ - 127 : 0);                       \
        const int up_ = dpp_shr1_i32(En_);                                \
        E = (!big_ && lane > 0) ? (up_ - 32) : En_;                       \
        const int upE_ = dpp_shr1_i32(E);                                 \
        int d_ = upE_ - E;                                                \
        d_ = d_ > 52 ? 52 : d_;                                           \
        d_ = d_ < -126 ? -126 : d_;                                       \
        delta = d_;                                                       \
    }

    const int NS = hlen - 1;       // steps t = 1..NS
    const int nfull = NS >> 2;     // full 4-step blocks
    float lpA[16], lpB[16];
    LOADQ(lpA, 0);                 // block 0 (t=1..4)

    int blk = 0;
    for (; blk + 2 <= nfull; blk += 2) {
        LOADQ(lpB, blk + 1);
        STEP4(lpA);
        LOADQ(lpA, blk + 2);
        STEP4(lpB);
        RENORM();                  // every 8 steps
    }
    if (blk < nfull) {             // leftover full block, data in lpA
        STEP4(lpA);
    }
    // tail steps (0..3): t = 4*nfull+1 .. NS
    for (int tt = 4 * nfull + 1; tt <= NS; ++tt) {
        float lt[16];
        lt[0]  = s_pT[y0 - 1][tt + 3];
        lt[4]  = s_pT[y1 - 1][tt + 3];
        lt[8]  = s_pT[y2 - 1][tt + 3];
        lt[12] = s_pT[y3 - 1][tt + 3];
        STEPX(aA, aB, lt, 0);
#pragma unroll
        for (int i = 0; i < 9; ++i) aA[i] = aB[i];
    }

    // ---- readout: merge per-lane frames in f64 ----
#pragma unroll
    for (int i = 0; i < 8; ++i) s_beta[8 * lane + i] = aA[i];
    if (lane == 63) s_beta[512] = aA[8];
    s_E[lane] = E;
    s_red[lane] = lg2;
    __syncthreads();
    if (lane == 0) {
        double lg2tot = 0.0;
        for (int i = 0; i < 64; ++i) lg2tot += s_red[i];
        const int i1 = 2 * lb - 1, i2 = 2 * lb;
        int l1 = i1 >> 3; if (l1 > 63) l1 = 63;
        int l2 = i2 >> 3; if (l2 > 63) l2 = 63;
        const int E1 = s_E[l1], E2 = s_E[l2];
        const int Em = (E1 > E2) ? E1 : E2;
        double s = ldexp((double)s_beta[i1], E1 - Em)
                 + ldexp((double)s_beta[i2], E2 - Em);
        double nlld = -(log(s) + ((double)Em + lg2tot) * LN2D);
        float nll = (float)nlld;
        if (!(fabsf(nll) < 1e8f)) nll = 0.f;   // zero_infinity (±inf / NaN)
        nll_out[b] = nll;
    }
#undef STEPX
#undef STEP4
#undef LOADQ
#undef LD4F
#undef RENORM
}

// Kernel 3: deterministic reduction of 32 per-sample NLLs -> loss.
__global__ __launch_bounds__(64) void k_finalize(
    const float* __restrict__ nll, float* __restrict__ out)
{
    int tid = threadIdx.x;
    float v = (tid < B_DIM) ? nll[tid] : 0.f;
#pragma unroll
    for (int off = 32; off; off >>= 1) v += __shfl_down(v, off, 64);
    if (tid == 0) out[0] = v / (float)B_DIM;
}

extern "C" void kernel_launch(void* const* d_in, const int* in_sizes, int n_in,
                              void* d_out, int out_size, void* d_ws, size_t ws_size,
                              hipStream_t stream) {
    const float* hs      = (const float*)d_in[0];
    const float* W       = (const float*)d_in[1];
    const float* bias    = (const float*)d_in[2];
    const int*   hlens   = (const int*)d_in[3];
    const int*   ys_pad  = (const int*)d_in[4];
    const int*   ys_lens = (const int*)d_in[5];

    float* out   = (float*)d_out;
    float* logp  = out + 1;                                      // (B,T,V) log-softmax
    float* probs = out + 1 + (size_t)B_DIM * T_DIM * V_DIM;      // (B,T,V) softmax
    float* nll   = (float*)d_ws;                                 // 32 floats

    hipLaunchKernelGGL(k_logits_softmax, dim3(1024), dim3(256), 0, stream,
                       hs, W, bias, logp, probs);
    hipLaunchKernelGGL(k_ctc, dim3(B_DIM), dim3(64), 0, stream,
                       probs, ys_pad, hlens, ys_lens, nll);
    hipLaunchKernelGGL(k_finalize, dim3(1), dim3(64), 0, stream, nll, out);
}

// Round 14
// 127.462 us; speedup vs baseline: 2.5081x; 1.1265x over previous
//
#include <hip/hip_runtime.h>
#include <math.h>

#define B_DIM 32
#define T_DIM 2048
#define D_DIM 512
#define V_DIM 5
#define L_DIM 256
#define LN2D 0.6931471805599453
#define TP (T_DIM + 4)

typedef const float __attribute__((address_space(1)))* gas_fp;
typedef float __attribute__((address_space(3)))* las_fp;

// ---- DPP helpers (VALU cross-lane, no DS pipe) ----
__device__ __forceinline__ float dpp_shr1_f32(float x) {
    return __int_as_float(__builtin_amdgcn_update_dpp(
        0, __float_as_int(x), 0x138, 0xf, 0xf, true));  // wave_shr:1, lane0->0
}
__device__ __forceinline__ int dpp_shr1_i32(int x) {
    return __builtin_amdgcn_update_dpp(0, x, 0x138, 0xf, 0xf, true);
}
__device__ __forceinline__ float wave_fsum_dpp(float x) {
    // canonical GCN full-wave sum; total lands in lane 63
    x += __int_as_float(__builtin_amdgcn_update_dpp(0, __float_as_int(x), 0x111, 0xf, 0xf, true));
    x += __int_as_float(__builtin_amdgcn_update_dpp(0, __float_as_int(x), 0x112, 0xf, 0xf, true));
    x += __int_as_float(__builtin_amdgcn_update_dpp(0, __float_as_int(x), 0x114, 0xf, 0xf, true));
    x += __int_as_float(__builtin_amdgcn_update_dpp(0, __float_as_int(x), 0x118, 0xf, 0xf, true));
    x += __int_as_float(__builtin_amdgcn_update_dpp(0, __float_as_int(x), 0x142, 0xa, 0xf, false));
    x += __int_as_float(__builtin_amdgcn_update_dpp(0, __float_as_int(x), 0x143, 0xc, 0xf, false));
    return x;
}

// Kernel 1: wave-per-row GEMV + softmax (coalesced; r11-proven).
__global__ __launch_bounds__(256) void k_logits_softmax(
    const float* __restrict__ hs, const float* __restrict__ W,
    const float* __restrict__ bias, float* __restrict__ logp,
    float* __restrict__ probs)
{
    const int lane = threadIdx.x & 63;
    const int wid  = (blockIdx.x * blockDim.x + threadIdx.x) >> 6;
    const int nwav = (gridDim.x * blockDim.x) >> 6;

    float wr[2][4][V_DIM];
#pragma unroll
    for (int c = 0; c < 2; ++c)
#pragma unroll
        for (int j = 0; j < 4; ++j) {
            const int k = c * 256 + lane * 4 + j;
#pragma unroll
            for (int v = 0; v < V_DIM; ++v) wr[c][j][v] = W[k * V_DIM + v];
        }
    float br[V_DIM];
#pragma unroll
    for (int v = 0; v < V_DIM; ++v) br[v] = bias[v];

    for (int row = wid; row < B_DIM * T_DIM; row += nwav) {
        const float* x = hs + (size_t)row * D_DIM;
        float4 xa = *reinterpret_cast<const float4*>(x + lane * 4);
        float4 xb = *reinterpret_cast<const float4*>(x + 256 + lane * 4);
        const float xs0[4] = {xa.x, xa.y, xa.z, xa.w};
        const float xs1[4] = {xb.x, xb.y, xb.z, xb.w};

        float acc[V_DIM];
#pragma unroll
        for (int v = 0; v < V_DIM; ++v) acc[v] = 0.f;
#pragma unroll
        for (int j = 0; j < 4; ++j)
#pragma unroll
            for (int v = 0; v < V_DIM; ++v) {
                acc[v] = fmaf(xs0[j], wr[0][j][v], acc[v]);
                acc[v] = fmaf(xs1[j], wr[1][j][v], acc[v]);
            }
#pragma unroll
        for (int v = 0; v < V_DIM; ++v) acc[v] = wave_fsum_dpp(acc[v]);

        if (lane == 63) {
#pragma unroll
            for (int v = 0; v < V_DIM; ++v) acc[v] += br[v];
            float m = fmaxf(fmaxf(fmaxf(acc[0], acc[1]), fmaxf(acc[2], acc[3])), acc[4]);
            float e[V_DIM], s = 0.f;
#pragma unroll
            for (int v = 0; v < V_DIM; ++v) { e[v] = __expf(acc[v] - m); s += e[v]; }
            float lse = m + __logf(s);
            float inv = 1.f / s;
            size_t base = (size_t)row * V_DIM;
#pragma unroll
            for (int v = 0; v < V_DIM; ++v) {
                logp[base + v]  = acc[v] - lse;
                probs[base + v] = e[v] * inv;
            }
        }
    }
}

// Kernel 2: CTC forward scan — blank-normalized f32 per-lane BFP (r13-proven
// numerics) with instruction-count trims. Cross-round evidence (r8: 27
// instr/step=180cy; r11: 24,f64=152; r13: 24,f32=149) shows a single-wave
// ISSUE-CADENCE bound (~5-6cy/instruction, dtype-independent), so count is
// the lever:
// (a) ZERO-ROW: Sb=2lb+1 is always ODD, so the first invalid state is odd;
//     pointing invalid odd states' ratio pointers at an all-zero LDS row
//     locks all invalid states to exactly 0 -> vmask deleted everywhere.
// (b) delta folded into per-renorm constants ds=2^delta (exact f32) and
//     skd0=sk0*ds -> per-step ldexpf deleted (N0 = fma(p7,ds,O0)).
// (c) batch-8 loads (8 x ds_read_b128 per 8 steps, double-buffered one full
//     group ahead) -> one waitcnt point per 8 steps, amortized addressing.
// (d) adopt bias 32->16 (same delta clamp [-126,52]: overflow-safe bound
//     2^(53+2+8*9)<inf unchanged, tolerance for upstream E advance doubles).
__global__ __launch_bounds__(64) void k_ctc(
    const float* __restrict__ probs, const int* __restrict__ ys_pad,
    const int* __restrict__ hlens, const int* __restrict__ ys_lens,
    float* __restrict__ nll_out)
{
    __shared__ float  s_probs[T_DIM * V_DIM];               // f32 staging
    __shared__ __align__(16) float s_pT[5][TP];             // rows 0..3: ratios; row 4: zeros
    __shared__ float  s_beta[513];
    __shared__ int    s_E[64];
    __shared__ double s_red[64];

    const int b    = blockIdx.x;
    const int lane = threadIdx.x;        // 0..63
    const int hlen = hlens[b];
    const int lb   = ys_lens[b];
    const int Sb   = 2 * lb + 1;
    const float* pb = probs + (size_t)b * T_DIM * V_DIM;
    const int*  yrow = ys_pad + b * L_DIM;

    // ---- stage all T*V probs into LDS (f32) ----
    for (int i = 0; i < (T_DIM * V_DIM) / 64; ++i) {
        __builtin_amdgcn_global_load_lds((gas_fp)(pb + i * 64 + lane),
                                         (las_fp)(&s_probs[i * 64]), 4, 0, 0);
    }
    asm volatile("s_waitcnt vmcnt(0)" ::: "memory");

    // ---- zero row (locks invalid odd states to 0) ----
    for (int i = lane; i < TP; i += 64) s_pT[4][i] = 0.f;

    // ---- transpose: blank-ratios r_t[y]=p_t[y]/p_t[blank] + sum log2(pb) ----
    double lg2 = 0.0;
    for (int i = 0; i < T_DIM / 64; ++i) {
        const int t = i * 64 + lane;
        const float* sp = &s_probs[t * 5];
        const float p0 = sp[0];
        const float inv = 1.0f / p0;
        s_pT[0][t + 3] = sp[1] * inv;
        s_pT[1][t + 3] = sp[2] * inv;
        s_pT[2][t + 3] = sp[3] * inv;
        s_pT[3][t + 3] = sp[4] * inv;
        if (t < hlen) {
            int ee; float mm = frexpf(p0, &ee);
            lg2 += (double)ee + (double)__log2f(mm);
        }
    }

    // labels for this lane's 4 odd states (8l+{1,3,5,7} -> labels 4l..4l+3)
    const int y0 = yrow[4 * lane + 0];
    const int y1 = yrow[4 * lane + 1];
    const int y2 = yrow[4 * lane + 2];
    const int y3 = yrow[4 * lane + 3];
    const int ym1 = (lane > 0) ? yrow[4 * lane - 1] : -1;

    const float sk0 = ((lane > 0) && (y0 != ym1)) ? 1.f : 0.f;
    const float sk1 = (y1 != y0) ? 1.f : 0.f;
    const float sk2 = (y2 != y1) ? 1.f : 0.f;
    const float sk3 = (y3 != y2) ? 1.f : 0.f;

    // ratio row pointers; invalid odd states -> zero row (locked to 0)
    const float* q_y0 = (8 * lane + 1 < Sb) ? &s_pT[y0 - 1][0] : &s_pT[4][0];
    const float* q_y1 = (8 * lane + 3 < Sb) ? &s_pT[y1 - 1][0] : &s_pT[4][0];
    const float* q_y2 = (8 * lane + 5 < Sb) ? &s_pT[y2 - 1][0] : &s_pT[4][0];
    const float* q_y3 = (8 * lane + 7 < Sb) ? &s_pT[y3 - 1][0] : &s_pT[4][0];

    float aA[9], aB[9];
#pragma unroll
    for (int i = 0; i < 9; ++i) aA[i] = 0.f;
    if (lane == 0) {
        aA[0] = 1.f;                     // beta_0[0]
        aA[1] = s_pT[y0 - 1][3];         // beta_0[1] = r_0[y0]
    }
    int E = 0;           // per-LANE frame exponent (true = rel * 2^E)
    float ds = 1.f;      // 2^delta (exact pow2), delta = E_prev - E
    float skd0 = sk0;    // sk0 * ds

#define LD4F(d, p)                                                        \
    { float4 u_ = *(const float4*)(p);                                    \
      (d)[0] = u_.x; (d)[1] = u_.y; (d)[2] = u_.z; (d)[3] = u_.w; }

// 8-step group load: rows stride-4, two 4-step sub-blocks at +0 / +16
#define LOADO(dst, gg)                                                    \
    { const int off_ = 4 + 8 * (gg);                                      \
      LD4F(dst + 0,  q_y0 + off_); LD4F(dst + 16, q_y0 + off_ + 4);       \
      LD4F(dst + 4,  q_y1 + off_); LD4F(dst + 20, q_y1 + off_ + 4);       \
      LD4F(dst + 8,  q_y2 + off_); LD4F(dst + 24, q_y2 + off_ + 4);       \
      LD4F(dst + 12, q_y3 + off_); LD4F(dst + 28, q_y3 + off_ + 4); }

// blank-normalized f32 step; frame delta pre-folded into ds / skd0.
#define STEPX(O, N, L, s_)                                                \
    {                                                                     \
        float p7_ = dpp_shr1_f32(O[7]);                                   \
        N[7] = fmaf(sk3, O[5], O[7] + O[6]) * L[12 + (s_)];               \
        N[2] = O[2] + O[1];                                               \
        N[3] = fmaf(sk1, O[1], O[3] + O[2]) * L[4 + (s_)];                \
        N[4] = O[4] + O[3];                                               \
        N[5] = fmaf(sk2, O[3], O[5] + O[4]) * L[8 + (s_)];                \
        N[6] = O[6] + O[5];                                               \
        N[8] = O[8] + O[7];                                               \
        N[0] = fmaf(p7_, ds, O[0]);                                       \
        N[1] = fmaf(skd0, p7_, O[1] + O[0]) * L[0 + (s_)];                \
    }

#define STEP8(L)                                                          \
    STEPX(aA, aB, L, 0);  STEPX(aB, aA, L, 1);                            \
    STEPX(aA, aB, L, 2);  STEPX(aB, aA, L, 3);                            \
    STEPX(aA, aB, L, 16); STEPX(aB, aA, L, 17);                           \
    STEPX(aA, aB, L, 18); STEPX(aB, aA, L, 19);

// Per-lane exact-pow2 renorm every 8 steps (no masks: invalid states are 0).
// Saturating scale (em<=253) and delta clamp [-126,52] keep inf/NaN
// unreachable (r13-proven). Empty lanes (max==0) adopt upstream E-16.
#define RENORM()                                                          \
    {                                                                     \
        float m_ = aA[0];                                                 \
        _Pragma("unroll")                                                 \
        for (int i_ = 1; i_ < 9; ++i_) m_ = fmaxf(m_, aA[i_]);            \
        const bool big_ = (m_ >= 1e-12f);                                 \
        int em_ = (__float_as_int(m_) >> 23) & 0xff;                      \
        em_ = em_ > 253 ? 253 : em_;                                      \
        const float sc_ = __int_as_float((254 - (big_ ? em_ : 127)) << 23); \
        _Pragma("unroll")                                                 \
        for (int i_ = 0; i_ < 9; ++i_) aA[i_] *= sc_;                     \
        const int En_ = E + (big_ ? em_ - 127 : 0);                       \
        const int up_ = dpp_shr1_i32(En_);                                \
        E = (!big_ && lane > 0) ? (up_ - 16) : En_;                       \
        const int upE_ = dpp_shr1_i32(E);                                 \
        int d_ = upE_ - E;                                                \
        d_ = d_ > 52 ? 52 : d_;                                           \
        d_ = d_ < -126 ? -126 : d_;                                       \
        ds = __int_as_float((127 + d_) << 23);                            \
        skd0 = sk0 * ds;                                                  \
    }

    const int NS = hlen - 1;       // steps t = 1..NS
    const int ngrp = NS >> 3;      // full 8-step groups (>=127 since hlen>=1024)
    float lpA[32], lpB[32];
    LOADO(lpA, 0);                 // group 0 (t=1..8)

    int g = 0;
    for (; g + 2 <= ngrp; g += 2) {
        LOADO(lpB, g + 1);
        STEP8(lpA);
        RENORM();
        LOADO(lpA, g + 2);
        STEP8(lpB);
        RENORM();
    }
    if (g < ngrp) {                // leftover full group, data in lpA
        STEP8(lpA);
        RENORM();
    }
    // tail steps (0..7): t = 8*ngrp+1 .. NS
    for (int tt = 8 * ngrp + 1; tt <= NS; ++tt) {
        float lt[16];
        lt[0]  = q_y0[tt + 3];
        lt[4]  = q_y1[tt + 3];
        lt[8]  = q_y2[tt + 3];
        lt[12] = q_y3[tt + 3];
        STEPX(aA, aB, lt, 0);
#pragma unroll
        for (int i = 0; i < 9; ++i) aA[i] = aB[i];
    }

    // ---- readout: merge per-lane frames in f64 ----
#pragma unroll
    for (int i = 0; i < 8; ++i) s_beta[8 * lane + i] = aA[i];
    if (lane == 63) s_beta[512] = aA[8];
    s_E[lane] = E;
    s_red[lane] = lg2;
    __syncthreads();
    if (lane == 0) {
        double lg2tot = 0.0;
        for (int i = 0; i < 64; ++i) lg2tot += s_red[i];
        const int i1 = 2 * lb - 1, i2 = 2 * lb;
        int l1 = i1 >> 3; if (l1 > 63) l1 = 63;
        int l2 = i2 >> 3; if (l2 > 63) l2 = 63;
        const int E1 = s_E[l1], E2 = s_E[l2];
        const int Em = (E1 > E2) ? E1 : E2;
        double s = ldexp((double)s_beta[i1], E1 - Em)
                 + ldexp((double)s_beta[i2], E2 - Em);
        double nlld = -(log(s) + ((double)Em + lg2tot) * LN2D);
        float nll = (float)nlld;
        if (!(fabsf(nll) < 1e8f)) nll = 0.f;   // zero_infinity (±inf / NaN)
        nll_out[b] = nll;
    }
#undef STEPX
#undef STEP8
#undef LOADO
#undef LD4F
#undef RENORM
}

// Kernel 3: deterministic reduction of 32 per-sample NLLs -> loss.
__global__ __launch_bounds__(64) void k_finalize(
    const float* __restrict__ nll, float* __restrict__ out)
{
    int tid = threadIdx.x;
    float v = (tid < B_DIM) ? nll[tid] : 0.f;
#pragma unroll
    for (int off = 32; off; off >>= 1) v += __shfl_down(v, off, 64);
    if (tid == 0) out[0] = v / (float)B_DIM;
}

extern "C" void kernel_launch(void* const* d_in, const int* in_sizes, int n_in,
                              void* d_out, int out_size, void* d_ws, size_t ws_size,
                              hipStream_t stream) {
    const float* hs      = (const float*)d_in[0];
    const float* W       = (const float*)d_in[1];
    const float* bias    = (const float*)d_in[2];
    const int*   hlens   = (const int*)d_in[3];
    const int*   ys_pad  = (const int*)d_in[4];
    const int*   ys_lens = (const int*)d_in[5];

    float* out   = (float*)d_out;
    float* logp  = out + 1;                                      // (B,T,V) log-softmax
    float* probs = out + 1 + (size_t)B_DIM * T_DIM * V_DIM;      // (B,T,V) softmax
    float* nll   = (float*)d_ws;                                 // 32 floats

    hipLaunchKernelGGL(k_logits_softmax, dim3(1024), dim3(256), 0, stream,
                       hs, W, bias, logp, probs);
    hipLaunchKernelGGL(k_ctc, dim3(B_DIM), dim3(64), 0, stream,
                       probs, ys_pad, hlens, ys_lens, nll);
    hipLaunchKernelGGL(k_finalize, dim3(1), dim3(64), 0, stream, nll, out);
}